// Round 7
// baseline (853.243 us; speedup 1.0000x reference)
//
#include <hip/hip_runtime.h>

#define HID   51
#define T_LEN 512
#define BT    8          // batch elems per block
#define NTH   256        // 4 waves, 1 per SIMD, 4 tile-slots each

// LDS float offsets in the 13312-float (52 KB) arena.
#define X_OFF   0        // 8 x 516
#define OUT_OFF 4128     // 8 x 516
#define H1_OFF  8256     // h1 B-frag: 2 parity x (2 kt x {hi,lo} x 256 words)
#define H2_OFF  10304    // h2 B-frag: same (ends 12352 <= 13312)

typedef _Float16 h8 __attribute__((ext_vector_type(8)));
typedef float    f4 __attribute__((ext_vector_type(4)));

__device__ __forceinline__ float fast_rcp(float x) { return __builtin_amdgcn_rcpf(x); }
__device__ __forceinline__ float sigm(float x) { return fast_rcp(1.0f + __expf(-x)); }
__device__ __forceinline__ float tanh_f(float x) {
    x = fminf(15.0f, fmaxf(-15.0f, x));
    float e = __expf(2.0f * x);
    return (e - 1.0f) * fast_rcp(e + 1.0f);
}

// lane col<->col^8 swap within each 16-lane row (D-tile column dimension)
__device__ __forceinline__ float dpp_ror8(float v) {
    int t = __builtin_amdgcn_update_dpp(0, __float_as_int(v), 0x128, 0xf, 0xf, true);
    return __int_as_float(t);
}

// read 8 fp32 from LDS, split into f16 hi + lo fragments (hi+lo ~ 2^-22 rel)
__device__ __forceinline__ void cvt_frag(const float* p, h8& hi, h8& lo) {
    float4 a = *(const float4*)p;
    float4 b = *(const float4*)(p + 4);
    float v[8] = {a.x, a.y, a.z, a.w, b.x, b.y, b.z, b.w};
    #pragma unroll
    for (int j = 0; j < 8; ++j) {
        _Float16 h = (_Float16)v[j];
        hi[j] = h;
        lo[j] = (_Float16)(v[j] - (float)h);
    }
}

__device__ __forceinline__ float gate_update(const float G[4], float& c) {
    float iv = sigm(G[0]), fv = sigm(G[1]), gv = tanh_f(G[2]), ov = sigm(G[3]);
    c = fv * c + iv * gv;
    return ov * tanh_f(c);
}

#define MFMA16(A, B, C) __builtin_amdgcn_mfma_f32_16x16x32_f16((A), (B), (C), 0, 0, 0)

// 1 wave/EU: RA budget = full 512-reg unified file. 192 weight regs (AGPR)
// + ~130 live VGPRs will NOT fit a 2-wave (256-reg) budget -> must pin.
__global__ __launch_bounds__(NTH, 1) __attribute__((amdgpu_waves_per_eu(1, 1)))
void lstm_seq_kernel(const float* __restrict__ x,
                     const float* __restrict__ W_ih1, const float* __restrict__ b_ih1,
                     const float* __restrict__ W_hh1, const float* __restrict__ b_hh1,
                     const float* __restrict__ W_ih2, const float* __restrict__ b_ih2,
                     const float* __restrict__ W_hh2, const float* __restrict__ b_hh2,
                     const float* __restrict__ fc_w,  const float* __restrict__ fc_b,
                     float* __restrict__ out)
{
    __shared__ __align__(16) float sb[13312];   // 52 KB arena

    const int tid   = threadIdx.x;
    const int b0    = blockIdx.x * BT;
    const int w     = tid >> 6;          // wave id 0..3
    const int lane  = tid & 63;
    const int row16 = lane & 15;         // A-frag M row within tile
    const int q4    = lane >> 4;         // k-chunk / D row-quad
    const int col   = row16;             // D column (batch; 8..15 pad)

    // 4 tile-slots per wave: {w, w+4, w+8, 12}. Slot 3 = tile 12 on all waves
    // (dup on waves 1..3: identical computation, benign).
    int mts[4];
    mts[0] = w; mts[1] = w + 4; mts[2] = w + 8; mts[3] = 12;

    // ============ weight staging (ROW-PERMUTED: row' = 4j + gate) ============
    h8 a1h[4][2], a1l[4][2];   // L1: W_hh1', K padded 51->64
    h8 a2h[4][4], a2l[4][4];   // L2: [W_ih2' | W_hh2'+fc], K padded 102->128

    // image 1: W_hh1 permuted [208][64]
    for (int i = tid; i < 208 * 64; i += NTH) {
        int rp = i >> 6, k = i & 63;
        int j = rp >> 2, g = rp & 3;
        sb[i] = (j < HID && k < HID) ? W_hh1[(g * HID + j) * HID + k] : 0.0f;
    }
    __syncthreads();
    #pragma unroll
    for (int s = 0; s < 4; ++s)
        #pragma unroll
        for (int kt = 0; kt < 2; ++kt)
            cvt_frag(sb + (mts[s] * 16 + row16) * 64 + kt * 32 + q4 * 8, a1h[s][kt], a1l[s][kt]);
    __syncthreads();

    // image 2: W_ih2 permuted -> L2 k-tiles 0,1 (h1 half)
    for (int i = tid; i < 208 * 64; i += NTH) {
        int rp = i >> 6, k = i & 63;
        int j = rp >> 2, g = rp & 3;
        sb[i] = (j < HID && k < HID) ? W_ih2[(g * HID + j) * HID + k] : 0.0f;
    }
    __syncthreads();
    #pragma unroll
    for (int s = 0; s < 4; ++s)
        #pragma unroll
        for (int kt = 0; kt < 2; ++kt)
            cvt_frag(sb + (mts[s] * 16 + row16) * 64 + kt * 32 + q4 * 8, a2h[s][kt], a2l[s][kt]);
    __syncthreads();

    // image 3: W_hh2 permuted + fc_w as permuted row 204 -> L2 k-tiles 2,3 (h2 half)
    for (int i = tid; i < 208 * 64; i += NTH) {
        int rp = i >> 6, k = i & 63;
        int j = rp >> 2, g = rp & 3;
        float v = 0.0f;
        if (k < HID) {
            if (j < HID)        v = W_hh2[(g * HID + j) * HID + k];
            else if (rp == 204) v = fc_w[k];
        }
        sb[i] = v;
    }
    __syncthreads();
    #pragma unroll
    for (int s = 0; s < 4; ++s)
        #pragma unroll
        for (int kt = 0; kt < 2; ++kt)
            cvt_frag(sb + (mts[s] * 16 + row16) * 64 + kt * 32 + q4 * 8, a2h[s][kt + 2], a2l[s][kt + 2]);
    __syncthreads();

    // ============ per-lane gate constants: TWO (j, b) tasks per lane ============
    // col<8 lanes own slots 0,1 at batch=col; col>=8 own slots 2,3 at batch=col-8
    const int jA = 4 * ((col < 8) ? mts[0] : mts[2]) + q4;
    const int jB = 4 * ((col < 8) ? mts[1] : mts[3]) + q4;
    const int bsel = col & 7;
    float bsr1A[4], wr1A[4], bsr2A[4], bsr1B[4], wr1B[4], bsr2B[4];
    #pragma unroll
    for (int g = 0; g < 4; ++g) {
        if (jA < HID) {
            int r = g * HID + jA;
            bsr1A[g] = b_ih1[r] + b_hh1[r]; wr1A[g] = W_ih1[r]; bsr2A[g] = b_ih2[r] + b_hh2[r];
        } else { bsr1A[g] = 0.f; wr1A[g] = 0.f; bsr2A[g] = 0.f; }
        if (jB < HID) {
            int r = g * HID + jB;
            bsr1B[g] = b_ih1[r] + b_hh1[r]; wr1B[g] = W_ih1[r]; bsr2B[g] = b_ih2[r] + b_hh2[r];
        } else { bsr1B[g] = 0.f; wr1B[g] = 0.f; bsr2B[g] = 0.f; }
    }
    const bool valA = (jA < HID), valB = (jB < HID);
    const int offA = (jA >> 5) * 1024 + ((((jA & 31) >> 3) << 4) + bsel) * 8 + (jA & 7);
    const int offB = (jB >> 5) * 1024 + ((((jB & 31) >> 3) << 4) + bsel) * 8 + (jB & 7);

    // ============ runtime buffers ============
    float* xl   = sb + X_OFF;    // [b][516]
    float* outl = sb + OUT_OFF;  // [b][516]
    for (int i = tid; i < BT * T_LEN; i += NTH) {
        int b = i >> 9, t = i & (T_LEN - 1);
        xl[b * 516 + t] = x[(size_t)(b0 + b) * T_LEN + t];
    }
    for (int i = tid; i < 4096; i += NTH) sb[H1_OFF + i] = 0.0f;  // h1+h2, both parities

    float c1A = 0.f, c1B = 0.f, c2A = 0.f, c2B = 0.f;
    const float fcb = fc_b[0];
    const bool outlane = (w == 0) && (q4 == 3) && (col < 8);
    __syncthreads();

    // ============ recurrence: 2 barriers/step ============
    for (int t = 0; t <= T_LEN; ++t) {
        const int pw = t & 1, pr = pw ^ 1;

        // ---- phase 1: read h1(t-1)/h2(t-1) [pr]; L1 full + L2 h2-half MFMAs ----
        const float* rA = sb + H1_OFF + pr * 1024 + lane * 4;
        const float* rB = sb + H2_OFF + pr * 1024 + lane * 4;
        h8 bh0 = *(const h8*)(rA);       h8 bl0 = *(const h8*)(rA + 256);
        h8 bh1 = *(const h8*)(rA + 512); h8 bl1 = *(const h8*)(rA + 768);
        h8 ch2 = *(const h8*)(rB);       h8 cl2 = *(const h8*)(rB + 256);
        h8 ch3 = *(const h8*)(rB + 512); h8 cl3 = *(const h8*)(rB + 768);

        const f4 z = {0.f, 0.f, 0.f, 0.f};
        f4 P[4], Q[4], R[4], U[4], V[4], W[4];
        #pragma unroll
        for (int s = 0; s < 4; ++s) {
            P[s] = z; Q[s] = z; R[s] = z;
            P[s] = MFMA16(a1h[s][0], bh0, P[s]); P[s] = MFMA16(a1h[s][1], bh1, P[s]);
            Q[s] = MFMA16(a1h[s][0], bl0, Q[s]); Q[s] = MFMA16(a1h[s][1], bl1, Q[s]);
            R[s] = MFMA16(a1l[s][0], bh0, R[s]); R[s] = MFMA16(a1l[s][1], bh1, R[s]);
        }
        #pragma unroll
        for (int s = 0; s < 4; ++s) {
            U[s] = z; V[s] = z; W[s] = z;
            U[s] = MFMA16(a2h[s][2], ch2, U[s]); U[s] = MFMA16(a2h[s][3], ch3, U[s]);
            V[s] = MFMA16(a2h[s][2], cl2, V[s]); V[s] = MFMA16(a2h[s][3], cl3, V[s]);
            W[s] = MFMA16(a2l[s][2], ch2, W[s]); W[s] = MFMA16(a2l[s][3], ch3, W[s]);
        }

        // ---- gates 1: two gate blocks per lane (slots 2,3 routed via ror8) ----
        f4 s4[4];
        #pragma unroll
        for (int s = 0; s < 4; ++s) s4[s] = P[s] + Q[s] + R[s];
        float xv = (t < T_LEN) ? xl[bsel * 516 + t] : 0.0f;
        float GA[4], GB[4];
        #pragma unroll
        for (int g = 0; g < 4; ++g) {
            float r2 = dpp_ror8(s4[2][g]);
            float r3 = dpp_ror8(s4[3][g]);
            GA[g] = ((col < 8) ? s4[0][g] : r2) + bsr1A[g] + wr1A[g] * xv;
            GB[g] = ((col < 8) ? s4[1][g] : r3) + bsr1B[g] + wr1B[g] * xv;
        }
        _Float16* wp1 = (_Float16*)(sb + H1_OFF + pw * 1024);
        {
            float hv = gate_update(GA, c1A);
            _Float16 hh = (_Float16)hv, hl = (_Float16)(hv - (float)hh);
            if (valA) { wp1[offA] = hh; wp1[offA + 512] = hl; }
        }
        {
            float hv = gate_update(GB, c1B);
            _Float16 hh = (_Float16)hv, hl = (_Float16)(hv - (float)hh);
            if (valB) { wp1[offB] = hh; wp1[offB + 512] = hl; }
        }
        __syncthreads();

        // ---- phase 2: read h1(t) [pw]; finish L2 ----
        const float* rC = sb + H1_OFF + pw * 1024 + lane * 4;
        h8 ch0 = *(const h8*)(rC);       h8 cl0 = *(const h8*)(rC + 256);
        h8 ch1 = *(const h8*)(rC + 512); h8 cl1 = *(const h8*)(rC + 768);
        #pragma unroll
        for (int s = 0; s < 4; ++s) {
            U[s] = MFMA16(a2h[s][0], ch0, U[s]); U[s] = MFMA16(a2h[s][1], ch1, U[s]);
            V[s] = MFMA16(a2h[s][0], cl0, V[s]); V[s] = MFMA16(a2h[s][1], cl1, V[s]);
            W[s] = MFMA16(a2l[s][0], ch0, W[s]); W[s] = MFMA16(a2l[s][1], ch1, W[s]);
        }

        // ---- gates 2 + fc output ----
        f4 u4[4];
        #pragma unroll
        for (int s = 0; s < 4; ++s) u4[s] = U[s] + V[s] + W[s];
        float fcv = u4[3][0];   // wave0/q4=3/col<8: permuted row 204 = fc . h2(t-1)
        float G2A[4], G2B[4];
        #pragma unroll
        for (int g = 0; g < 4; ++g) {
            float r2 = dpp_ror8(u4[2][g]);
            float r3 = dpp_ror8(u4[3][g]);
            G2A[g] = ((col < 8) ? u4[0][g] : r2) + bsr2A[g];
            G2B[g] = ((col < 8) ? u4[1][g] : r3) + bsr2B[g];
        }
        _Float16* wp2 = (_Float16*)(sb + H2_OFF + pw * 1024);
        {
            float hv = gate_update(G2A, c2A);
            _Float16 hh = (_Float16)hv, hl = (_Float16)(hv - (float)hh);
            if (valA) { wp2[offA] = hh; wp2[offA + 512] = hl; }
        }
        {
            float hv = gate_update(G2B, c2B);
            _Float16 hh = (_Float16)hv, hl = (_Float16)(hv - (float)hh);
            if (valB) { wp2[offB] = hh; wp2[offB + 512] = hl; }
        }
        if (outlane && t >= 1) outl[col * 516 + (t - 1)] = fcb + fcv;
        __syncthreads();
    }

    // ---- write outputs (coalesced) ----
    for (int i = tid; i < BT * T_LEN; i += NTH) {
        int b = i >> 9, tt = i & (T_LEN - 1);
        out[(size_t)(b0 + b) * T_LEN + tt] = outl[b * 516 + tt];
    }
}

extern "C" void kernel_launch(void* const* d_in, const int* in_sizes, int n_in,
                              void* d_out, int out_size, void* d_ws, size_t ws_size,
                              hipStream_t stream) {
    const float* x      = (const float*)d_in[0];
    // d_in[1] = future (scalar, always 0 here) -> ignored
    const float* W_ih1  = (const float*)d_in[2];
    const float* b_ih1v = (const float*)d_in[3];
    const float* W_hh1  = (const float*)d_in[4];
    const float* b_hh1v = (const float*)d_in[5];
    const float* W_ih2  = (const float*)d_in[6];
    const float* b_ih2v = (const float*)d_in[7];
    const float* W_hh2  = (const float*)d_in[8];
    const float* b_hh2v = (const float*)d_in[9];
    const float* fc_w   = (const float*)d_in[10];
    const float* fc_b   = (const float*)d_in[11];
    float* out = (float*)d_out;

    dim3 grid(2048 / BT);   // 256 blocks -> 1 block/CU
    dim3 block(NTH);
    lstm_seq_kernel<<<grid, block, 0, stream>>>(x, W_ih1, b_ih1v, W_hh1, b_hh1v,
                                                W_ih2, b_ih2v, W_hh2, b_hh2v,
                                                fc_w, fc_b, out);
}

// Round 8
// 661.398 us; speedup vs baseline: 1.2901x; 1.2901x over previous
//
#include <hip/hip_runtime.h>

#define HID   51
#define T_LEN 512
#define BT    8          // batch elems per block
#define NTH   512        // 8 waves, 2/SIMD (r6 shape — r7's 1/SIMD regressed)

// LDS float offsets in the 13312-float (52 KB) arena.
#define X_OFF   0        // 8 x 516
#define OUT_OFF 4128     // 8 x 516
#define H1_OFF  8256     // h1 B-frag: 2 parity x (2 kt x {hi,lo} x 256 words)
#define H2_OFF  10304    // h2 B-frag: same (ends 12352 <= 13312)

typedef _Float16 h8 __attribute__((ext_vector_type(8)));
typedef float    f4 __attribute__((ext_vector_type(4)));

__device__ __forceinline__ float fast_rcp(float x) { return __builtin_amdgcn_rcpf(x); }
__device__ __forceinline__ float sigm(float x) { return fast_rcp(1.0f + __expf(-x)); }
__device__ __forceinline__ float tanh_f(float x) {
    x = fminf(15.0f, fmaxf(-15.0f, x));
    float e = __expf(2.0f * x);
    return (e - 1.0f) * fast_rcp(e + 1.0f);
}

// lane col<->col^8 swap within each 16-lane row (D-tile column dimension)
__device__ __forceinline__ float dpp_ror8(float v) {
    int t = __builtin_amdgcn_update_dpp(0, __float_as_int(v), 0x128, 0xf, 0xf, true);
    return __int_as_float(t);
}

// read 8 fp32 from LDS, split into f16 hi + lo fragments (hi+lo ~ 2^-22 rel)
__device__ __forceinline__ void cvt_frag(const float* p, h8& hi, h8& lo) {
    float4 a = *(const float4*)p;
    float4 b = *(const float4*)(p + 4);
    float v[8] = {a.x, a.y, a.z, a.w, b.x, b.y, b.z, b.w};
    #pragma unroll
    for (int j = 0; j < 8; ++j) {
        _Float16 h = (_Float16)v[j];
        hi[j] = h;
        lo[j] = (_Float16)(v[j] - (float)h);
    }
}

__device__ __forceinline__ float gate_update(const float G[4], float& c) {
    float iv = sigm(G[0]), fv = sigm(G[1]), gv = tanh_f(G[2]), ov = sigm(G[3]);
    c = fv * c + iv * gv;
    return ov * tanh_f(c);
}

#define MFMA16(A, B, C) __builtin_amdgcn_mfma_f32_16x16x32_f16((A), (B), (C), 0, 0, 0)

__global__ __launch_bounds__(NTH, 2)
void lstm_seq_kernel(const float* __restrict__ x,
                     const float* __restrict__ W_ih1, const float* __restrict__ b_ih1,
                     const float* __restrict__ W_hh1, const float* __restrict__ b_hh1,
                     const float* __restrict__ W_ih2, const float* __restrict__ b_ih2,
                     const float* __restrict__ W_hh2, const float* __restrict__ b_hh2,
                     const float* __restrict__ fc_w,  const float* __restrict__ fc_b,
                     float* __restrict__ out)
{
    __shared__ __align__(16) float sb[13312];   // 52 KB arena

    const int tid   = threadIdx.x;
    const int b0    = blockIdx.x * BT;
    const int w     = tid >> 6;          // wave id 0..7
    const int lane  = tid & 63;
    const int row16 = lane & 15;         // A-frag M row within tile
    const int q4    = lane >> 4;         // k-chunk / D row-quad
    const int col   = row16;             // D column (batch; 8..15 pad)

    // tile assignment: waves 0..3 -> {2w,2w+1}; waves 4..7 -> {8..11, 12}
    const int mt0 = (w < 4) ? 2 * w     : 4 + w;
    const int mt1 = (w < 4) ? 2 * w + 1 : 12;

    // ============ weight staging (ROW-PERMUTED: row' = 4j + gate) ============
    h8 a1h[2][2], a1l[2][2];   // L1: W_hh1', K padded 51->64
    h8 a2h[2][4], a2l[2][4];   // L2: [W_ih2' | W_hh2'+fc], K padded 102->128

    // image 1: W_hh1 permuted [208][64]
    for (int i = tid; i < 208 * 64; i += NTH) {
        int rp = i >> 6, k = i & 63;
        int j = rp >> 2, g = rp & 3;
        sb[i] = (j < HID && k < HID) ? W_hh1[(g * HID + j) * HID + k] : 0.0f;
    }
    __syncthreads();
    #pragma unroll
    for (int s = 0; s < 2; ++s) {
        int mt = s ? mt1 : mt0;
        #pragma unroll
        for (int kt = 0; kt < 2; ++kt)
            cvt_frag(sb + (mt * 16 + row16) * 64 + kt * 32 + q4 * 8, a1h[s][kt], a1l[s][kt]);
    }
    __syncthreads();

    // image 2: W_ih2 permuted -> L2 k-tiles 0,1 (h1 half)
    for (int i = tid; i < 208 * 64; i += NTH) {
        int rp = i >> 6, k = i & 63;
        int j = rp >> 2, g = rp & 3;
        sb[i] = (j < HID && k < HID) ? W_ih2[(g * HID + j) * HID + k] : 0.0f;
    }
    __syncthreads();
    #pragma unroll
    for (int s = 0; s < 2; ++s) {
        int mt = s ? mt1 : mt0;
        #pragma unroll
        for (int kt = 0; kt < 2; ++kt)
            cvt_frag(sb + (mt * 16 + row16) * 64 + kt * 32 + q4 * 8, a2h[s][kt], a2l[s][kt]);
    }
    __syncthreads();

    // image 3: W_hh2 permuted + fc_w as permuted row 204 -> L2 k-tiles 2,3 (h2 half)
    for (int i = tid; i < 208 * 64; i += NTH) {
        int rp = i >> 6, k = i & 63;
        int j = rp >> 2, g = rp & 3;
        float v = 0.0f;
        if (k < HID) {
            if (j < HID)        v = W_hh2[(g * HID + j) * HID + k];
            else if (rp == 204) v = fc_w[k];
        }
        sb[i] = v;
    }
    __syncthreads();
    #pragma unroll
    for (int s = 0; s < 2; ++s) {
        int mt = s ? mt1 : mt0;
        #pragma unroll
        for (int kt = 0; kt < 2; ++kt)
            cvt_frag(sb + (mt * 16 + row16) * 64 + kt * 32 + q4 * 8, a2h[s][kt + 2], a2l[s][kt + 2]);
    }
    __syncthreads();

    // ============ per-lane gate constants: ONE (j, b) per lane ============
    const int jj0  = 4 * mt0 + q4;
    const int jj1  = 4 * mt1 + q4;
    const int jsel = (col < 8) ? jj0 : jj1;
    const int bsel = col & 7;
    float bsr1[4], wr1[4], bsr2[4];
    #pragma unroll
    for (int g = 0; g < 4; ++g) {
        if (jsel < HID) {
            int r = g * HID + jsel;          // original row = gate*51 + j
            bsr1[g] = b_ih1[r] + b_hh1[r];
            wr1[g]  = W_ih1[r];
            bsr2[g] = b_ih2[r] + b_hh2[r];
        } else { bsr1[g] = 0.f; wr1[g] = 0.f; bsr2[g] = 0.f; }
    }
    const bool val  = (jsel < HID);
    const int  base = ((((jsel & 31) >> 3) << 4) + bsel) * 8 + (jsel & 7);
    const int  offh = (jsel >> 5) * 1024 + base;   // half-index within parity image

    // ============ runtime buffers ============
    float* xl   = sb + X_OFF;    // [b][516]
    float* outl = sb + OUT_OFF;  // [b][516]
    for (int i = tid; i < BT * T_LEN; i += NTH) {
        int b = i >> 9, t = i & (T_LEN - 1);
        xl[b * 516 + t] = x[(size_t)(b0 + b) * T_LEN + t];
    }
    for (int i = tid; i < 4096; i += NTH) sb[H1_OFF + i] = 0.0f;  // h1+h2, both parities

    float c1 = 0.f, c2 = 0.f;
    const float fcb = fc_b[0];
    const bool outlane = (w == 7) && (q4 == 3) && (col < 8);
    __syncthreads();

    // ============ prologue: h1(0) from x(0) alone (h1(-1)=0), write parity 0 ====
    {
        float xv = xl[bsel * 516 + 0];
        float G[4];
        #pragma unroll
        for (int g = 0; g < 4; ++g) G[g] = bsr1[g] + wr1[g] * xv;
        float hv = gate_update(G, c1);
        _Float16 hh = (_Float16)hv, hl = (_Float16)(hv - (float)hh);
        _Float16* wp = (_Float16*)(sb + H1_OFF + 0 * 1024);
        if (val) { wp[offh] = hh; wp[offh + 512] = hl; }
    }
    __syncthreads();

    // ============ merged recurrence: ONE barrier per body ============
    // body i: reads h1(i), h2(i-1) [parity i&1]
    //   -> full L2(i)  (h2(i) via gates2)  + full L1 for h1(i+1) via gates1
    //   -> writes h2(i), h1(i+1) [parity (i&1)^1]; out(i-1) from L2 row 204
    for (int i = 0; i <= T_LEN; ++i) {
        const int p = i & 1;
        const float* rA = sb + H1_OFF + p * 1024 + lane * 4;   // h1(i)
        const float* rB = sb + H2_OFF + p * 1024 + lane * 4;   // h2(i-1)
        h8 bh0 = *(const h8*)(rA);       h8 bl0 = *(const h8*)(rA + 256);
        h8 bh1 = *(const h8*)(rA + 512); h8 bl1 = *(const h8*)(rA + 768);
        h8 ch2 = *(const h8*)(rB);       h8 cl2 = *(const h8*)(rB + 256);
        h8 ch3 = *(const h8*)(rB + 512); h8 cl3 = *(const h8*)(rB + 768);

        const f4 z = {0.f, 0.f, 0.f, 0.f};
        // L2(i): depth-4 chains, 3 per slot
        f4 U0 = z, V0 = z, W0 = z, U1 = z, V1 = z, W1 = z;
        U0 = MFMA16(a2h[0][0], bh0, U0); U0 = MFMA16(a2h[0][1], bh1, U0);
        U0 = MFMA16(a2h[0][2], ch2, U0); U0 = MFMA16(a2h[0][3], ch3, U0);
        V0 = MFMA16(a2h[0][0], bl0, V0); V0 = MFMA16(a2h[0][1], bl1, V0);
        V0 = MFMA16(a2h[0][2], cl2, V0); V0 = MFMA16(a2h[0][3], cl3, V0);
        W0 = MFMA16(a2l[0][0], bh0, W0); W0 = MFMA16(a2l[0][1], bh1, W0);
        W0 = MFMA16(a2l[0][2], ch2, W0); W0 = MFMA16(a2l[0][3], ch3, W0);
        U1 = MFMA16(a2h[1][0], bh0, U1); U1 = MFMA16(a2h[1][1], bh1, U1);
        U1 = MFMA16(a2h[1][2], ch2, U1); U1 = MFMA16(a2h[1][3], ch3, U1);
        V1 = MFMA16(a2h[1][0], bl0, V1); V1 = MFMA16(a2h[1][1], bl1, V1);
        V1 = MFMA16(a2h[1][2], cl2, V1); V1 = MFMA16(a2h[1][3], cl3, V1);
        W1 = MFMA16(a2l[1][0], bh0, W1); W1 = MFMA16(a2l[1][1], bh1, W1);
        W1 = MFMA16(a2l[1][2], ch2, W1); W1 = MFMA16(a2l[1][3], ch3, W1);
        // L1 (for h1(i+1)): depth-2 chains, 3 per slot
        f4 P0 = z, Q0 = z, R0 = z, P1 = z, Q1 = z, R1 = z;
        P0 = MFMA16(a1h[0][0], bh0, P0); P0 = MFMA16(a1h[0][1], bh1, P0);
        Q0 = MFMA16(a1h[0][0], bl0, Q0); Q0 = MFMA16(a1h[0][1], bl1, Q0);
        R0 = MFMA16(a1l[0][0], bh0, R0); R0 = MFMA16(a1l[0][1], bh1, R0);
        P1 = MFMA16(a1h[1][0], bh0, P1); P1 = MFMA16(a1h[1][1], bh1, P1);
        Q1 = MFMA16(a1h[1][0], bl0, Q1); Q1 = MFMA16(a1h[1][1], bl1, Q1);
        R1 = MFMA16(a1l[1][0], bh0, R1); R1 = MFMA16(a1l[1][1], bh1, R1);

        // ---- gates2(i): h2(i) -> parity p^1; fc row 204 = out(i-1) ----
        f4 u0 = U0 + V0 + W0;
        f4 u1 = U1 + V1 + W1;
        float fcv = u1[0];   // wave7/q4=3/col<8: permuted row 204 = fc . h2(i-1)
        float u1r[4], G2[4];
        #pragma unroll
        for (int g = 0; g < 4; ++g) u1r[g] = dpp_ror8(u1[g]);
        #pragma unroll
        for (int g = 0; g < 4; ++g)
            G2[g] = ((col < 8) ? u0[g] : u1r[g]) + bsr2[g];
        // ---- gates1(i+1): h1(i+1) -> parity p^1 ----
        f4 s0 = P0 + Q0 + R0;
        f4 s1 = P1 + Q1 + R1;
        float s1r[4], G1[4];
        #pragma unroll
        for (int g = 0; g < 4; ++g) s1r[g] = dpp_ror8(s1[g]);
        float xv = (i + 1 < T_LEN) ? xl[bsel * 516 + i + 1] : 0.0f;
        #pragma unroll
        for (int g = 0; g < 4; ++g)
            G1[g] = ((col < 8) ? s0[g] : s1r[g]) + bsr1[g] + wr1[g] * xv;

        float hv2 = gate_update(G2, c2);
        float hv1 = gate_update(G1, c1);
        _Float16 hh2 = (_Float16)hv2, hl2 = (_Float16)(hv2 - (float)hh2);
        _Float16 hh1 = (_Float16)hv1, hl1 = (_Float16)(hv1 - (float)hh1);
        _Float16* wp2 = (_Float16*)(sb + H2_OFF + (p ^ 1) * 1024);
        _Float16* wp1 = (_Float16*)(sb + H1_OFF + (p ^ 1) * 1024);
        if (val) {
            wp2[offh] = hh2; wp2[offh + 512] = hl2;
            wp1[offh] = hh1; wp1[offh + 512] = hl1;
        }
        if (outlane && i >= 1) outl[col * 516 + (i - 1)] = fcb + fcv;
        __syncthreads();
    }

    // ---- write outputs (coalesced) ----
    for (int i = tid; i < BT * T_LEN; i += NTH) {
        int b = i >> 9, tt = i & (T_LEN - 1);
        out[(size_t)(b0 + b) * T_LEN + tt] = outl[b * 516 + tt];
    }
}

extern "C" void kernel_launch(void* const* d_in, const int* in_sizes, int n_in,
                              void* d_out, int out_size, void* d_ws, size_t ws_size,
                              hipStream_t stream) {
    const float* x      = (const float*)d_in[0];
    // d_in[1] = future (scalar, always 0 here) -> ignored
    const float* W_ih1  = (const float*)d_in[2];
    const float* b_ih1v = (const float*)d_in[3];
    const float* W_hh1  = (const float*)d_in[4];
    const float* b_hh1v = (const float*)d_in[5];
    const float* W_ih2  = (const float*)d_in[6];
    const float* b_ih2v = (const float*)d_in[7];
    const float* W_hh2  = (const float*)d_in[8];
    const float* b_hh2v = (const float*)d_in[9];
    const float* fc_w   = (const float*)d_in[10];
    const float* fc_b   = (const float*)d_in[11];
    float* out = (float*)d_out;

    dim3 grid(2048 / BT);   // 256 blocks -> 1 block/CU
    dim3 block(NTH);
    lstm_seq_kernel<<<grid, block, 0, stream>>>(x, W_ih1, b_ih1v, W_hh1, b_hh1v,
                                                W_ih2, b_ih2v, W_hh2, b_hh2v,
                                                fc_w, fc_b, out);
}

// Round 9
// 581.747 us; speedup vs baseline: 1.4667x; 1.1369x over previous
//
#include <hip/hip_runtime.h>

#define HID   51
#define T_LEN 512
#define BT    8          // batch elems per block
#define NTH   512        // 8 waves, 2/SIMD

// LDS float offsets in the 13312-float (52 KB) arena.
#define X_OFF   0        // 8 x 516
#define OUT_OFF 4128     // 8 x 516
#define H1_OFF  8256     // h1 B-frag: 2 parity x (2 kt x {hi,lo} x 256 words)
#define H2_OFF  10304    // h2 B-frag: same (ends 12352 <= 13312)

typedef _Float16 h8 __attribute__((ext_vector_type(8)));
typedef float    f4 __attribute__((ext_vector_type(4)));

__device__ __forceinline__ float fast_rcp(float x) { return __builtin_amdgcn_rcpf(x); }
__device__ __forceinline__ float sigm(float x) { return fast_rcp(1.0f + __expf(-x)); }
__device__ __forceinline__ float tanh_f(float x) {
    x = fminf(15.0f, fmaxf(-15.0f, x));
    float e = __expf(2.0f * x);
    return (e - 1.0f) * fast_rcp(e + 1.0f);
}

// lane col<->col^8 swap within each 16-lane row (D-tile column dimension)
__device__ __forceinline__ float dpp_ror8(float v) {
    int t = __builtin_amdgcn_update_dpp(0, __float_as_int(v), 0x128, 0xf, 0xf, true);
    return __int_as_float(t);
}

// read 8 fp32 from LDS, split into f16 hi + lo fragments (hi+lo ~ 2^-22 rel)
__device__ __forceinline__ void cvt_frag(const float* p, h8& hi, h8& lo) {
    float4 a = *(const float4*)p;
    float4 b = *(const float4*)(p + 4);
    float v[8] = {a.x, a.y, a.z, a.w, b.x, b.y, b.z, b.w};
    #pragma unroll
    for (int j = 0; j < 8; ++j) {
        _Float16 h = (_Float16)v[j];
        hi[j] = h;
        lo[j] = (_Float16)(v[j] - (float)h);
    }
}

__device__ __forceinline__ float gate_update(const float G[4], float& c) {
    float iv = sigm(G[0]), fv = sigm(G[1]), gv = tanh_f(G[2]), ov = sigm(G[3]);
    c = fv * c + iv * gv;
    return ov * tanh_f(c);
}

#define MFMA16(A, B, C) __builtin_amdgcn_mfma_f32_16x16x32_f16((A), (B), (C), 0, 0, 0)

__global__ __launch_bounds__(NTH, 2)
void lstm_seq_kernel(const float* __restrict__ x,
                     const float* __restrict__ W_ih1, const float* __restrict__ b_ih1,
                     const float* __restrict__ W_hh1, const float* __restrict__ b_hh1,
                     const float* __restrict__ W_ih2, const float* __restrict__ b_ih2,
                     const float* __restrict__ W_hh2, const float* __restrict__ b_hh2,
                     const float* __restrict__ fc_w,  const float* __restrict__ fc_b,
                     float* __restrict__ out)
{
    __shared__ __align__(16) float sb[13312];   // 52 KB arena

    const int tid   = threadIdx.x;
    const int b0    = blockIdx.x * BT;
    const int w     = tid >> 6;          // wave id 0..7
    const int lane  = tid & 63;
    const int row16 = lane & 15;         // A-frag M row within tile
    const int q4    = lane >> 4;         // k-chunk / D row-quad
    const int col   = row16;             // D column (batch; 8..15 pad)

    // tile assignment: waves 0..3 -> {2w,2w+1}; waves 4..7 -> {8..11, 12}
    const int mt0 = (w < 4) ? 2 * w     : 4 + w;
    const int mt1 = (w < 4) ? 2 * w + 1 : 12;

    // ============ weight staging (ROW-PERMUTED: row' = 4j + gate) ============
    h8 a1h[2][2], a1l[2][2];   // L1: W_hh1', K padded 51->64
    h8 a2h[2][4], a2l[2][4];   // L2: [W_ih2' | W_hh2'+fc], K padded 102->128

    // image 1: W_hh1 permuted [208][64]
    for (int i = tid; i < 208 * 64; i += NTH) {
        int rp = i >> 6, k = i & 63;
        int j = rp >> 2, g = rp & 3;
        sb[i] = (j < HID && k < HID) ? W_hh1[(g * HID + j) * HID + k] : 0.0f;
    }
    __syncthreads();
    #pragma unroll
    for (int s = 0; s < 2; ++s) {
        int mt = s ? mt1 : mt0;
        #pragma unroll
        for (int kt = 0; kt < 2; ++kt)
            cvt_frag(sb + (mt * 16 + row16) * 64 + kt * 32 + q4 * 8, a1h[s][kt], a1l[s][kt]);
    }
    __syncthreads();

    // image 2: W_ih2 permuted -> L2 k-tiles 0,1 (h1 half)
    for (int i = tid; i < 208 * 64; i += NTH) {
        int rp = i >> 6, k = i & 63;
        int j = rp >> 2, g = rp & 3;
        sb[i] = (j < HID && k < HID) ? W_ih2[(g * HID + j) * HID + k] : 0.0f;
    }
    __syncthreads();
    #pragma unroll
    for (int s = 0; s < 2; ++s) {
        int mt = s ? mt1 : mt0;
        #pragma unroll
        for (int kt = 0; kt < 2; ++kt)
            cvt_frag(sb + (mt * 16 + row16) * 64 + kt * 32 + q4 * 8, a2h[s][kt], a2l[s][kt]);
    }
    __syncthreads();

    // image 3: W_hh2 permuted + fc_w as permuted row 204 -> L2 k-tiles 2,3 (h2 half)
    for (int i = tid; i < 208 * 64; i += NTH) {
        int rp = i >> 6, k = i & 63;
        int j = rp >> 2, g = rp & 3;
        float v = 0.0f;
        if (k < HID) {
            if (j < HID)        v = W_hh2[(g * HID + j) * HID + k];
            else if (rp == 204) v = fc_w[k];
        }
        sb[i] = v;
    }
    __syncthreads();
    #pragma unroll
    for (int s = 0; s < 2; ++s) {
        int mt = s ? mt1 : mt0;
        #pragma unroll
        for (int kt = 0; kt < 2; ++kt)
            cvt_frag(sb + (mt * 16 + row16) * 64 + kt * 32 + q4 * 8, a2h[s][kt + 2], a2l[s][kt + 2]);
    }
    __syncthreads();

    // ============ per-slot bias C-init vectors (reg g <-> gate g, all cols) ====
    const int jj0 = 4 * mt0 + q4;
    const int jj1 = 4 * mt1 + q4;
    f4 bi1s0, bi1s1, bi2s0, bi2s1;
    #pragma unroll
    for (int g = 0; g < 4; ++g) {
        bi1s0[g] = (jj0 < HID) ? (b_ih1[g * HID + jj0] + b_hh1[g * HID + jj0]) : 0.f;
        bi1s1[g] = (jj1 < HID) ? (b_ih1[g * HID + jj1] + b_hh1[g * HID + jj1]) : 0.f;
        bi2s0[g] = (jj0 < HID) ? (b_ih2[g * HID + jj0] + b_hh2[g * HID + jj0]) : 0.f;
        bi2s1[g] = (jj1 < HID) ? (b_ih2[g * HID + jj1] + b_hh2[g * HID + jj1]) : 0.f;
    }

    // per-lane gate constants: ONE (j, b) per lane (col>=8 lanes take slot 1)
    const int jsel = (col < 8) ? jj0 : jj1;
    const int bsel = col & 7;
    float wr1[4];
    #pragma unroll
    for (int g = 0; g < 4; ++g)
        wr1[g] = (jsel < HID) ? W_ih1[g * HID + jsel] : 0.f;
    const bool val  = (jsel < HID);
    const int  base = ((((jsel & 31) >> 3) << 4) + bsel) * 8 + (jsel & 7);
    const int  offh = (jsel >> 5) * 1024 + base;   // half-index within parity image

    // ============ runtime buffers ============
    float* xl   = sb + X_OFF;    // [b][516]
    float* outl = sb + OUT_OFF;  // [b][516]
    for (int i = tid; i < BT * T_LEN; i += NTH) {
        int b = i >> 9, t = i & (T_LEN - 1);
        xl[b * 516 + t] = x[(size_t)(b0 + b) * T_LEN + t];
    }
    for (int i = tid; i < 4096; i += NTH) sb[H1_OFF + i] = 0.0f;  // h1+h2, both parities

    float c1 = 0.f, c2 = 0.f;
    const float fcb = fc_b[0];
    const bool outlane = (w == 7) && (q4 == 3) && (col < 8);
    const float* xp = xl + bsel * 516;            // hoisted x base
    const float* rA0 = sb + H1_OFF + lane * 4;    // parity-0 h1 read base
    const float* rB0 = sb + H2_OFF + lane * 4;    // parity-0 h2 read base
    __syncthreads();

    // ============ prologue: h1(0) from x(0) alone (h1(-1)=0), write parity 0 ====
    {
        float xv = xp[0];
        float G[4];
        #pragma unroll
        for (int g = 0; g < 4; ++g)
            G[g] = ((col < 8) ? bi1s0[g] : bi1s1[g]) + wr1[g] * xv;
        float hv = gate_update(G, c1);
        _Float16 hh = (_Float16)hv, hl = (_Float16)(hv - (float)hh);
        _Float16* wp = (_Float16*)(sb + H1_OFF);
        if (val) { wp[offh] = hh; wp[offh + 512] = hl; }
    }
    __syncthreads();

    // ============ merged recurrence: ONE barrier per body, 4 chained accums ====
    // body i: reads h1(i), h2(i-1) [parity i&1]
    //   -> L2(i) chain (bias-initialized) -> gates2 -> h2(i)
    //   -> L1 chain (bias-initialized)    -> gates1 -> h1(i+1)
    //   writes parity (i&1)^1; out(i-1) from L2 slot-1 row 204
    for (int i = 0; i <= T_LEN; ++i) {
        const int p = i & 1;
        const float* rA = rA0 + p * 1024;   // h1(i)
        const float* rB = rB0 + p * 1024;   // h2(i-1)
        h8 bh0 = *(const h8*)(rA);       h8 bl0 = *(const h8*)(rA + 256);
        h8 bh1 = *(const h8*)(rA + 512); h8 bl1 = *(const h8*)(rA + 768);
        h8 ch2 = *(const h8*)(rB);       h8 cl2 = *(const h8*)(rB + 256);
        h8 ch3 = *(const h8*)(rB + 512); h8 cl3 = *(const h8*)(rB + 768);

        // L2(i): one depth-12 chain per slot, C-initialized with layer-2 bias
        f4 u0 = bi2s0, u1 = bi2s1;
        u0 = MFMA16(a2h[0][0], bh0, u0); u1 = MFMA16(a2h[1][0], bh0, u1);
        u0 = MFMA16(a2l[0][0], bh0, u0); u1 = MFMA16(a2l[1][0], bh0, u1);
        u0 = MFMA16(a2h[0][0], bl0, u0); u1 = MFMA16(a2h[1][0], bl0, u1);
        u0 = MFMA16(a2h[0][1], bh1, u0); u1 = MFMA16(a2h[1][1], bh1, u1);
        u0 = MFMA16(a2l[0][1], bh1, u0); u1 = MFMA16(a2l[1][1], bh1, u1);
        u0 = MFMA16(a2h[0][1], bl1, u0); u1 = MFMA16(a2h[1][1], bl1, u1);
        u0 = MFMA16(a2h[0][2], ch2, u0); u1 = MFMA16(a2h[1][2], ch2, u1);
        u0 = MFMA16(a2l[0][2], ch2, u0); u1 = MFMA16(a2l[1][2], ch2, u1);
        u0 = MFMA16(a2h[0][2], cl2, u0); u1 = MFMA16(a2h[1][2], cl2, u1);
        u0 = MFMA16(a2h[0][3], ch3, u0); u1 = MFMA16(a2h[1][3], ch3, u1);
        u0 = MFMA16(a2l[0][3], ch3, u0); u1 = MFMA16(a2l[1][3], ch3, u1);
        u0 = MFMA16(a2h[0][3], cl3, u0); u1 = MFMA16(a2h[1][3], cl3, u1);
        // L1 (for h1(i+1)): one depth-6 chain per slot, C-initialized with bias
        f4 s0 = bi1s0, s1 = bi1s1;
        s0 = MFMA16(a1h[0][0], bh0, s0); s1 = MFMA16(a1h[1][0], bh0, s1);
        s0 = MFMA16(a1l[0][0], bh0, s0); s1 = MFMA16(a1l[1][0], bh0, s1);
        s0 = MFMA16(a1h[0][0], bl0, s0); s1 = MFMA16(a1h[1][0], bl0, s1);
        s0 = MFMA16(a1h[0][1], bh1, s0); s1 = MFMA16(a1h[1][1], bh1, s1);
        s0 = MFMA16(a1l[0][1], bh1, s0); s1 = MFMA16(a1l[1][1], bh1, s1);
        s0 = MFMA16(a1h[0][1], bl1, s0); s1 = MFMA16(a1h[1][1], bl1, s1);

        // ---- gates2(i): h2(i) -> parity p^1; fc row 204 = out(i-1) ----
        float fcv = u1[0];   // wave7/q4=3/col<8: permuted row 204 = fc . h2(i-1)
        float G2[4], G1[4];
        #pragma unroll
        for (int g = 0; g < 4; ++g) {
            float ur = dpp_ror8(u1[g]);
            G2[g] = (col < 8) ? u0[g] : ur;
        }
        float xv = (i + 1 < T_LEN) ? xp[i + 1] : 0.0f;
        #pragma unroll
        for (int g = 0; g < 4; ++g) {
            float sr = dpp_ror8(s1[g]);
            G1[g] = ((col < 8) ? s0[g] : sr) + wr1[g] * xv;
        }

        float hv2 = gate_update(G2, c2);
        float hv1 = gate_update(G1, c1);
        _Float16 hh2 = (_Float16)hv2, hl2 = (_Float16)(hv2 - (float)hh2);
        _Float16 hh1 = (_Float16)hv1, hl1 = (_Float16)(hv1 - (float)hh1);
        _Float16* wp2 = (_Float16*)(sb + H2_OFF + (p ^ 1) * 1024);
        _Float16* wp1 = (_Float16*)(sb + H1_OFF + (p ^ 1) * 1024);
        if (val) {
            wp2[offh] = hh2; wp2[offh + 512] = hl2;
            wp1[offh] = hh1; wp1[offh + 512] = hl1;
        }
        if (outlane && i >= 1) outl[col * 516 + (i - 1)] = fcb + fcv;
        __syncthreads();
    }

    // ---- write outputs (coalesced) ----
    for (int i = tid; i < BT * T_LEN; i += NTH) {
        int b = i >> 9, tt = i & (T_LEN - 1);
        out[(size_t)(b0 + b) * T_LEN + tt] = outl[b * 516 + tt];
    }
}

extern "C" void kernel_launch(void* const* d_in, const int* in_sizes, int n_in,
                              void* d_out, int out_size, void* d_ws, size_t ws_size,
                              hipStream_t stream) {
    const float* x      = (const float*)d_in[0];
    // d_in[1] = future (scalar, always 0 here) -> ignored
    const float* W_ih1  = (const float*)d_in[2];
    const float* b_ih1v = (const float*)d_in[3];
    const float* W_hh1  = (const float*)d_in[4];
    const float* b_hh1v = (const float*)d_in[5];
    const float* W_ih2  = (const float*)d_in[6];
    const float* b_ih2v = (const float*)d_in[7];
    const float* W_hh2  = (const float*)d_in[8];
    const float* b_hh2v = (const float*)d_in[9];
    const float* fc_w   = (const float*)d_in[10];
    const float* fc_b   = (const float*)d_in[11];
    float* out = (float*)d_out;

    dim3 grid(2048 / BT);   // 256 blocks -> 1 block/CU
    dim3 block(NTH);
    lstm_seq_kernel<<<grid, block, 0, stream>>>(x, W_ih1, b_ih1v, W_hh1, b_hh1v,
                                                W_ih2, b_ih2v, W_hh2, b_hh2v,
                                                fc_w, fc_b, out);
}